// Round 6
// baseline (406.160 us; speedup 1.0000x reference)
//
#include <hip/hip_runtime.h>
#include <cstddef>

#define B_   4
#define S_   8192
#define D_   512
#define H_   8
#define HD_  64
#define NROW (B_ * S_)              // 32768
#define NQ   ((size_t)NROW * D_)    // 16777216 elements per q/k/v buffer

typedef __attribute__((ext_vector_type(4))) float  f32x4;
typedef __attribute__((ext_vector_type(8))) short  s16x8;
typedef __attribute__((ext_vector_type(4))) unsigned short u16x4;
typedef __attribute__((ext_vector_type(8))) unsigned short u16x8;

__device__ __forceinline__ float phi_f(float x) {
    return x > 0.0f ? x + 1.0f : expf(x);   // elu(x)+1
}
__device__ __forceinline__ float bf2f(unsigned short u) {
    return __uint_as_float(((unsigned int)u) << 16);
}
__device__ __forceinline__ unsigned short f2bf(float f) {
    unsigned int u = __float_as_uint(f);
    u += 0x7fffu + ((u >> 16) & 1u);        // round-to-nearest-even
    return (unsigned short)(u >> 16);
}

#define GLOBAL_AS(p) ((const __attribute__((address_space(1))) void*)(p))
#define LDS_AS(p)    ((__attribute__((address_space(3))) void*)(p))

// ---------------------------------------------------------------------------
// Mask layout detector: 1 = byte-per-element (bool), 0 = 4-byte layout.
// ---------------------------------------------------------------------------
__global__ void detect_mask(const unsigned char* __restrict__ m, int* __restrict__ flag) {
    __shared__ int sany;
    if (threadIdx.x == 0) sany = 0;
    __syncthreads();
    int any = 0;
    for (int i = 1 + 4 * (int)threadIdx.x; i < NROW; i += 4 * 256) any |= m[i];
    if (any) atomicOr(&sany, 1);
    __syncthreads();
    if (threadIdx.x == 0) *flag = sany ? 1 : 0;
}

// ---------------------------------------------------------------------------
// Convert query/w_in/w_out -> bf16; mask -> float (1.0 keep / 0.0 ignore).
// ---------------------------------------------------------------------------
__global__ __launch_bounds__(256) void convert_all(
    const float* __restrict__ q,  unsigned short* __restrict__ qb,
    const float* __restrict__ wi, unsigned short* __restrict__ wib,
    const float* __restrict__ wo, unsigned short* __restrict__ wob,
    const unsigned char* __restrict__ kpm, const int* __restrict__ flag,
    float* __restrict__ fmask)
{
    const size_t i = (size_t)blockIdx.x * 256 + threadIdx.x;
    {   // query: 16777216 / 4 = 4194304 threads exactly
        const float4 v = *(const float4*)&q[i * 4];
        u16x4 o; o.x = f2bf(v.x); o.y = f2bf(v.y); o.z = f2bf(v.z); o.w = f2bf(v.w);
        *(u16x4*)&qb[i * 4] = o;
    }
    if (i < 786432 / 4) {
        const float4 v = *(const float4*)&wi[i * 4];
        u16x4 o; o.x = f2bf(v.x); o.y = f2bf(v.y); o.z = f2bf(v.z); o.w = f2bf(v.w);
        *(u16x4*)&wib[i * 4] = o;
    }
    if (i < 262144 / 4) {
        const float4 v = *(const float4*)&wo[i * 4];
        u16x4 o; o.x = f2bf(v.x); o.y = f2bf(v.y); o.z = f2bf(v.z); o.w = f2bf(v.w);
        *(u16x4*)&wob[i * 4] = o;
    }
    if (i < NROW) {
        const bool ignore = (*flag) ? (kpm[i] != 0) : (((const int*)kpm)[i] != 0);
        fmask[i] = ignore ? 0.0f : 1.0f;
    }
}

// ---------------------------------------------------------------------------
// R10: 256x256 8-phase bf16 MFMA GEMM — R9 + race fix.
//
// R9 raced: raw s_barrier is NOT a compiler fence; LLVM sank the register-only
// {lgkmcnt, MFMA} group past the phase-end barrier (rule #18 mechanism), so a
// wave could cross the barrier with its ds_reads still pending while another
// wave's global_load_lds stage overwrote that half-tile.  Pre-timing check
// passed (geometry/ledger correct); graph replays diverged nondeterministically.
//
// Fix: pin the phase skeleton with sched_barrier(0) at every structural point
// and make the lgkmcnt(0) explicit after the mid-barrier (m201 discipline):
//   LOAD ; STAGE ; SB0 ; s_barrier ; lgkmcnt(0) ; SB0 ;
//   setprio(1) MFMA setprio(0) ; SB0 ; [vmcnt] ; s_barrier ; SB0
// Per-phase granularity (16 pins/iter), not per-instruction (m141 pathology).
//
// Geometry/ledger (unchanged from R9, verified by its pre-timing pass):
// BM=BN=256, BK=64, 512 thr = 8 waves (wm=wv>>2, wn=wv&3); per-wave C=128x64
// interleaved (m-frag ig -> rows (ig*2+wm)*16, n-frag j -> cols (j*4+wn)*16);
// acc[8][4] f32x4.  LDS As/Bs[2][256][64] (128 KB), buf = tile parity.
// 8 gray-coded quadrant phases per 2 K-tiles; ONE half-tile stage per phase,
// death-tracked; vmcnt(4) only at ph4/ph8 (vmcnt(0) only last iter ph4).
// T2 swizzle: LDS(r,c)=G(r,c^(r&7)) via pre-swizzled global src (linear LDS
// dest); frag reads chunk (w2*4+cn)^(fr&7).  T1 XCD swizzle (nwg%8==0).
// ---------------------------------------------------------------------------
__global__ __launch_bounds__(512, 2) void gemm_mfma256(
    const unsigned short* __restrict__ A,  int lda,
    const unsigned short* __restrict__ Bw, int ldb,
    const float* __restrict__ bias, int K, int mode,
    const float* __restrict__ fmask,
    unsigned short* __restrict__ Cq,
    unsigned short* __restrict__ Ck,
    unsigned short* __restrict__ Cv,
    float* __restrict__ Cout)
{
    __shared__ __align__(16) unsigned short As[2][256][64];
    __shared__ __align__(16) unsigned short Bs[2][256][64];
    __shared__ float fm[256];

    const int t    = threadIdx.x;
    const int lane = t & 63;
    const int wv   = t >> 6;            // wave 0..7
    const int wm   = wv >> 2;           // 0..1
    const int wn   = wv & 3;            // 0..3

    // T1 XCD swizzle
    const int nbx = gridDim.x;
    const int nwg = nbx * gridDim.y;
    int id = blockIdx.y * nbx + blockIdx.x;
    id = (id & 7) * (nwg >> 3) + (id >> 3);
    const int m0 = (id / nbx) * 256;
    const int n0 = (id % nbx) * 256;

    if (mode == 0 && t < 256) fm[t] = fmask[m0 + t];

    f32x4 acc[8][4] = {};

    // staging lane constants (pre-swizzled source chunk)
    const int srow  = lane >> 3;                         // 0..7 row within 8-row slab
    const int clog8 = ((lane & 7) ^ (srow & 7)) * 8;     // source k-elem offset
    // frag-read lane constants
    const int fr  = lane & 15;
    const int fr7 = fr & 7;
    const int cn  = lane >> 4;                           // 0..3

    const int niter = K >> 7;           // iterations of 2 K-tiles

    #define SB0() __builtin_amdgcn_sched_barrier(0)

    // stage one half-tile (rows h*128..+128) of tile `tt` into DST
    #define STAGE_HALF(DST, SRC, ld, org, tt, h)                                     \
        do {                                                                         \
            _Pragma("unroll")                                                        \
            for (int l_ = 0; l_ < 2; ++l_) {                                         \
                const int rl_ = (h) * 128 + wv * 16 + l_ * 8;                        \
                const unsigned short* g_ = (SRC)                                     \
                    + (size_t)((org) + rl_ + srow) * (ld) + ((tt) << 6) + clog8;     \
                __builtin_amdgcn_global_load_lds(GLOBAL_AS(g_),                      \
                    LDS_AS(&DST[rl_][0]), 16, 0, 0);                                 \
            }                                                                        \
        } while (0)

    #define LOAD_AF(u, mh)                                                           \
        _Pragma("unroll")                                                            \
        for (int ii = 0; ii < 4; ++ii)                                               \
            _Pragma("unroll")                                                        \
            for (int w2 = 0; w2 < 2; ++w2)                                           \
                a[ii][w2] = *(const s16x8*)&As[u][(((mh)*4 + ii)*2 + wm)*16 + fr]    \
                                               [((w2*4 + cn) ^ fr7) * 8];

    #define LOAD_BF(u, nh)                                                           \
        _Pragma("unroll")                                                            \
        for (int jj = 0; jj < 2; ++jj)                                               \
            _Pragma("unroll")                                                        \
            for (int w2 = 0; w2 < 2; ++w2)                                           \
                b[jj][w2] = *(const s16x8*)&Bs[u][(((nh)*2 + jj)*4 + wn)*16 + fr]    \
                                               [((w2*4 + cn) ^ fr7) * 8];

    #define MFMA_Q(mh, nh)                                                           \
        __builtin_amdgcn_s_setprio(1);                                               \
        _Pragma("unroll")                                                            \
        for (int w2 = 0; w2 < 2; ++w2)                                               \
            _Pragma("unroll")                                                        \
            for (int ii = 0; ii < 4; ++ii)                                           \
                _Pragma("unroll")                                                    \
                for (int jj = 0; jj < 2; ++jj)                                       \
                    acc[(mh)*4 + ii][(nh)*2 + jj] =                                  \
                        __builtin_amdgcn_mfma_f32_16x16x32_bf16(                     \
                            a[ii][w2], b[jj][w2], acc[(mh)*4 + ii][(nh)*2 + jj],     \
                            0, 0, 0);                                                \
        __builtin_amdgcn_s_setprio(0);

    // fenced phase core: mid-barrier, explicit lgkmcnt, MFMA, optional vmcnt,
    // end-barrier — all pinned so nothing crosses phase boundaries.
    #define PHASE_CORE(mh, nh, VWAIT)                                                \
        SB0();                                                                       \
        __builtin_amdgcn_s_barrier();                                                \
        asm volatile("s_waitcnt lgkmcnt(0)" ::: "memory");                           \
        SB0();                                                                       \
        MFMA_Q(mh, nh)                                                               \
        SB0();                                                                       \
        VWAIT                                                                        \
        __builtin_amdgcn_s_barrier();                                                \
        SB0();

    #define VW_NONE
    #define VW_4  asm volatile("s_waitcnt vmcnt(4)" ::: "memory");
    #define VW_0  asm volatile("s_waitcnt vmcnt(0)" ::: "memory");

    s16x8 a[4][2], b[2][2];

    // ---- prologue ----
    STAGE_HALF(As[0], A,  lda, m0, 0, 0);
    STAGE_HALF(As[0], A,  lda, m0, 0, 1);
    STAGE_HALF(Bs[0], Bw, ldb, n0, 0, 0);
    STAGE_HALF(Bs[0], Bw, ldb, n0, 0, 1);
    STAGE_HALF(As[1], A,  lda, m0, 1, 0);
    STAGE_HALF(Bs[1], Bw, ldb, n0, 1, 1);
    SB0();
    asm volatile("s_waitcnt vmcnt(4)" ::: "memory");
    __builtin_amdgcn_s_barrier();
    SB0();

    for (int i = 0; i < niter; ++i) {
        const int more = (i < niter - 1);

        // ph1 (0,0) buf0; stage A(2i+1)h1 -> buf1
        LOAD_AF(0, 0) LOAD_BF(0, 0)
        STAGE_HALF(As[1], A, lda, m0, 2*i + 1, 1);
        PHASE_CORE(0, 0, VW_NONE)

        // ph2 (0,1) buf0; stage B(2i+1)h0 -> buf1
        LOAD_BF(0, 1)
        STAGE_HALF(Bs[1], Bw, ldb, n0, 2*i + 1, 0);
        PHASE_CORE(0, 1, VW_NONE)

        // ph3 (1,1) buf0; stage A(2i+2)h0 -> buf0
        LOAD_AF(0, 1)
        if (more) STAGE_HALF(As[0], A, lda, m0, 2*i + 2, 0);
        PHASE_CORE(1, 1, VW_NONE)

        // ph4 (1,0) buf0; stage B(2i+2)h1 -> buf0; wait covers ph5-8 (tile 2i+1)
        LOAD_BF(0, 0)
        if (more) STAGE_HALF(Bs[0], Bw, ldb, n0, 2*i + 2, 1);
        if (more) { PHASE_CORE(1, 0, VW_4) }
        else      { PHASE_CORE(1, 0, VW_0) }

        // ph5 (0,0) buf1; stage A(2i+2)h1 -> buf0
        LOAD_AF(1, 0) LOAD_BF(1, 0)
        if (more) STAGE_HALF(As[0], A, lda, m0, 2*i + 2, 1);
        PHASE_CORE(0, 0, VW_NONE)

        // ph6 (0,1) buf1; stage B(2i+2)h0 -> buf0
        LOAD_BF(1, 1)
        if (more) STAGE_HALF(Bs[0], Bw, ldb, n0, 2*i + 2, 0);
        PHASE_CORE(0, 1, VW_NONE)

        // ph7 (1,1) buf1; stage A(2i+3)h0 -> buf1
        LOAD_AF(1, 1)
        if (more) STAGE_HALF(As[1], A, lda, m0, 2*i + 3, 0);
        PHASE_CORE(1, 1, VW_NONE)

        // ph8 (1,0) buf1; stage B(2i+3)h1 -> buf1; wait covers next ph1 (tile 2i+2)
        LOAD_BF(1, 0)
        if (more) STAGE_HALF(Bs[1], Bw, ldb, n0, 2*i + 3, 1);
        PHASE_CORE(1, 0, VW_4)
    }

    #undef STAGE_HALF
    #undef LOAD_AF
    #undef LOAD_BF
    #undef MFMA_Q
    #undef PHASE_CORE
    #undef VW_NONE
    #undef VW_4
    #undef VW_0
    #undef SB0

    // Epilogue. C/D: col = lane&15, row = (lane>>4)*4 + reg.
    const int colf = lane & 15;
    const int rq   = (lane >> 4) * 4;
    float bj[4];
    #pragma unroll
    for (int j = 0; j < 4; ++j) bj[j] = bias[n0 + (j*4 + wn)*16 + colf];

    if (mode == 1) {
        #pragma unroll
        for (int ig = 0; ig < 8; ++ig)
            #pragma unroll
            for (int r = 0; r < 4; ++r) {
                const int m = m0 + (ig*2 + wm)*16 + rq + r;
                #pragma unroll
                for (int j = 0; j < 4; ++j) {
                    const int n = n0 + (j*4 + wn)*16 + colf;
                    Cout[(size_t)m * D_ + n] = acc[ig][j][r] + bj[j];
                }
            }
    } else {
        const int region = n0 >> 9;     // 0:q 1:k 2:v (BN=256 divides 512)
        unsigned short* Cb = region == 0 ? Cq : (region == 1 ? Ck : Cv);
        #pragma unroll
        for (int ig = 0; ig < 8; ++ig)
            #pragma unroll
            for (int r = 0; r < 4; ++r) {
                const int ml = (ig*2 + wm)*16 + rq + r;
                const int m  = m0 + ml;
                const float mk = fm[ml];
                #pragma unroll
                for (int j = 0; j < 4; ++j) {
                    const int n = (n0 & 511) + (j*4 + wn)*16 + colf;
                    float v = acc[ig][j][r] + bj[j];
                    if (region == 0)      v = phi_f(v);
                    else if (region == 1) v = phi_f(v) * mk;
                    else                  v = v * mk;
                    Cb[(size_t)m * D_ + n] = f2bf(v);
                }
            }
    }
}

// ---------------------------------------------------------------------------
// Partial kv = k^T v (64x64) and k_sum per (head, S-chunk, wave-group).
// 8x8 per-thread tile (16 FMA per ds_read_b128); block's 4 waves act as an
// s-split (4 extra partials); LDS rows padded to 68 floats; u16x8 staging.
// ---------------------------------------------------------------------------
__global__ __launch_bounds__(256) void kv_reduce(
    const unsigned short* __restrict__ kbuf,   // [NROW][512] bf16
    const unsigned short* __restrict__ vbuf,
    float* __restrict__ part_kv,               // [32*64][4096]
    float* __restrict__ part_ks)               // [32*64][64]
{
    const int bh = blockIdx.x, chunk = blockIdx.y;   // chunk 0..15
    const int b = bh >> 3, h = bh & 7;

    __shared__ __align__(16) float Ks[16][68];   // pad 64->68: staging writes conflict-free
    __shared__ __align__(16) float Vs[16][68];

    const int t    = threadIdx.x;
    const int wave = t >> 6;            // ss-group 0..3
    const int lane = t & 63;
    const int tx   = lane & 7;          // e-octet
    const int ty   = lane >> 3;         // d-octet

    // staging: threads 0..127 load K, 128..255 load V; 8 bf16 (16B) each
    const int sr = (t & 127) >> 3;      // row 0..15
    const int sc = (t & 7) * 8;         // col 0,8,..,56
    const unsigned short* src = (t < 128 ? kbuf : vbuf) + (size_t)b * S_ * D_ + h * HD_;
    float (*dst)[68] = (t < 128) ? Ks : Vs;

    float acc[8][8] = {};
    float ks[8] = {};
    const int s0 = chunk * (S_ / 16);   // 512 rows per chunk

    for (int it = 0; it < S_ / 16; it += 16) {
        const size_t s = (size_t)(s0 + it + sr);
        const u16x8 x = *(const u16x8*)&src[s * D_ + sc];
        __syncthreads();                // previous compute done, LDS free
        float4 f0, f1;
        f0.x = bf2f(x[0]); f0.y = bf2f(x[1]); f0.z = bf2f(x[2]); f0.w = bf2f(x[3]);
        f1.x = bf2f(x[4]); f1.y = bf2f(x[5]); f1.z = bf2f(x[6]); f1.w = bf2f(x[7]);
        *(float4*)&dst[sr][sc]     = f0;
        *(float4*)&dst[sr][sc + 4] = f1;
        __syncthreads();                // staging complete
        #pragma unroll
        for (int ss0 = 0; ss0 < 4; ++ss0) {
            const int ss = wave + ss0 * 4;
            const float4 a0 = *(const float4*)&Ks[ss][ty * 8];
            const float4 a1 = *(const float4*)&Ks[ss][ty * 8 + 4];
            const float4 v0 = *(const float4*)&Vs[ss][tx * 8];
            const float4 v1 = *(const float4*)&Vs[ss][tx * 8 + 4];
            const float av[8] = {a0.x, a0.y, a0.z, a0.w, a1.x, a1.y, a1.z, a1.w};
            const float vv[8] = {v0.x, v0.y, v0.z, v0.w, v1.x, v1.y, v1.z, v1.w};
            #pragma unroll
            for (int i2 = 0; i2 < 8; ++i2)
                #pragma unroll
                for (int j2 = 0; j2 < 8; ++j2)
                    acc[i2][j2] += av[i2] * vv[j2];
            if (tx == 0) {
                #pragma unroll
                for (int i2 = 0; i2 < 8; ++i2) ks[i2] += av[i2];
            }
        }
    }

    const int p = bh * 64 + chunk * 4 + wave;    // partial index
    float* pk = part_kv + (size_t)p * 4096;
    #pragma unroll
    for (int i2 = 0; i2 < 8; ++i2) {
        #pragma unroll
        for (int j4 = 0; j4 < 2; ++j4) {
            float4 o;
            o.x = acc[i2][j4 * 4 + 0]; o.y = acc[i2][j4 * 4 + 1];
            o.z = acc[i2][j4 * 4 + 2]; o.w = acc[i2][j4 * 4 + 3];
            *(float4*)&pk[(ty * 8 + i2) * 64 + tx * 8 + j4 * 4] = o;
        }
    }
    if (tx == 0) {
        float* ps = part_ks + (size_t)p * 64;
        #pragma unroll
        for (int i2 = 0; i2 < 8; ++i2) ps[ty * 8 + i2] = ks[i2];
    }
}

// ---------------------------------------------------------------------------
// Sum 64 partials; emit kv TRANSPOSED in bf16 ([e][d] = MFMA B[n][k] layout)
// and ksum in bf16.
// ---------------------------------------------------------------------------
__global__ void kv_reduce2(const float* __restrict__ part_kv,
                           const float* __restrict__ part_ks,
                           unsigned short* __restrict__ kvT,    // [32][64][64]
                           unsigned short* __restrict__ ksumb)  // [32][64]
{
    const int i = blockIdx.x * 256 + threadIdx.x;   // 512 blocks -> 131072 exact
    if (i < 32 * 4096) {
        const int bh = i >> 12, de = i & 4095;
        const int d = de >> 6, e = de & 63;
        float s = 0.0f;
        #pragma unroll
        for (int c = 0; c < 64; ++c) s += part_kv[(size_t)(bh * 64 + c) * 4096 + de];
        kvT[bh * 4096 + e * 64 + d] = f2bf(s);
    }
    if (i < 32 * 64) {
        const int bh = i >> 6, e = i & 63;
        float s = 0.0f;
        #pragma unroll
        for (int c = 0; c < 64; ++c) s += part_ks[(size_t)(bh * 64 + c) * 64 + e];
        ksumb[i] = f2bf(s);
    }
}

// ---------------------------------------------------------------------------
// attn via MFMA, no LDS, no barriers.
// Per block: 128 rows x one head.  numerator: A=qphi[m][k=d] (bf16, contig),
// B=kvT[n=e][k=d].  Denominator: one extra MFMA per m-frag with a B-frag that
// broadcasts ksum across all 16 n-cols -> every lane holds its rows' own
// denominator in the accumulator (division is lane-local).
// ---------------------------------------------------------------------------
__global__ __launch_bounds__(256) void apply_attn_mfma(
    const unsigned short* __restrict__ qphi,   // [NROW][512] bf16 (phi'd)
    const unsigned short* __restrict__ kvT,    // [32][64][64] bf16
    const unsigned short* __restrict__ ksumb,  // [32][64] bf16
    unsigned short* __restrict__ attnb)        // [NROW][512] bf16
{
    const int bh = blockIdx.x;
    const int b  = bh >> 3, h = bh & 7;
    const int m0 = blockIdx.y * 128;

    const int t    = threadIdx.x;
    const int lane = t & 63;
    const int wave = t >> 6;            // rows m0 + wave*32 .. +32
    const int fr   = lane & 15;
    const int fk   = (lane >> 4) * 8;
    const int row0 = m0 + wave * 32;

    const unsigned short* Ah = qphi + (size_t)(b * S_ + row0) * D_ + h * HD_;
    const unsigned short* Bh = kvT + bh * 4096;
    const unsigned short* Kh = ksumb + bh * 64;

    s16x8 af[2][2], bfr[2][4], bd[2];
    #pragma unroll
    for (int kc = 0; kc < 2; ++kc) {
        #pragma unroll
        for (int i = 0; i < 2; ++i)
            af[kc][i] = *(const s16x8*)&Ah[(size_t)(i * 16 + fr) * D_ + kc * 32 + fk];
        #pragma unroll
        for (int j = 0; j < 4; ++j)
            bfr[kc][j] = *(const s16x8*)&Bh[(j * 16 + fr) * 64 + kc * 32 + fk];
        bd[kc] = *(const s16x8*)&Kh[kc * 32 + fk];   // broadcast over fr
    }

    f32x4 acc[2][4] = {};
    f32x4 accd[2] = {};
    #pragma unroll
    for (int kc = 0; kc < 2; ++kc)
        #pragma unroll
        for (int i = 0; i < 2; ++i) {
            #pragma unroll
            for (int j = 0; j < 4; ++j)
                acc[i][j] = __builtin_amdgcn_mfma_f32_16x16x32_bf16(af[kc][i], bfr[kc][j], acc[i][j], 0, 0, 0);
            accd[i] = __builtin_amdgcn_mfma_f32_16x16x32_bf16(af[kc][i], bd[kc], accd[i], 0, 0, 0);
        }

    // C/D layout: col = lane&15 (=fr), row = (lane>>4)*4 + reg
    const int rq = (lane >> 4) * 4;
    #pragma unroll
    for (int i = 0; i < 2; ++i)
        #pragma unroll
        for (int r = 0; r < 4; ++r) {
            const float inv = 1.0f / fmaxf(accd[i][r], 1e-6f);
            const size_t row = (size_t)(b * S_ + row0 + i * 16 + rq + r);
            #pragma unroll
            for (int j = 0; j < 4; ++j)
                attnb[row * D_ + h * HD_ + j * 16 + fr] = f2bf(acc[i][j][r] * inv);
        }
}

// ---------------------------------------------------------------------------
extern "C" void kernel_launch(void* const* d_in, const int* in_sizes, int n_in,
                              void* d_out, int out_size, void* d_ws, size_t ws_size,
                              hipStream_t stream)
{
    const float* query       = (const float*)d_in[0];
    const unsigned char* kpm = (const unsigned char*)d_in[3];
    const float* w_in        = (const float*)d_in[4];
    const float* b_in        = (const float*)d_in[5];
    const float* w_out       = (const float*)d_in[6];
    const float* b_out       = (const float*)d_in[7];
    float* out = (float*)d_out;

    // workspace layout (attn aliases qb, which is dead after in-proj)
    unsigned short* qb    = (unsigned short*)d_ws;          // query bf16 / attn bf16  33.5 MB
    unsigned short* qphi  = qb    + NQ;                     // phi(q)         33.5 MB
    unsigned short* kpb   = qphi  + NQ;                     // phi(k)*mask    33.5 MB
    unsigned short* vmb   = kpb   + NQ;                     // v*mask         33.5 MB
    unsigned short* wib   = vmb   + NQ;                     // w_in bf16       1.6 MB
    unsigned short* wob   = wib   + 1536 * 512;             // w_out bf16      0.5 MB
    float* fmask   = (float*)(wob + 512 * 512);             // 128 KB
    float* part_kv = fmask + NROW;                          // 32*64 partials: 32 MB
    float* part_ks = part_kv + (size_t)2048 * 4096;         // 512 KB
    unsigned short* kvTb  = (unsigned short*)(part_ks + 2048 * 64);  // 256 KB
    unsigned short* ksumb = kvTb + 32 * 4096;               // 4 KB
    int*   flag    = (int*)(ksumb + 32 * 64);

    hipLaunchKernelGGL(detect_mask, dim3(1), dim3(256), 0, stream, kpm, flag);
    hipLaunchKernelGGL(convert_all, dim3(16384), dim3(256), 0, stream,
                       query, qb, w_in, wib, w_out, wob, kpm, flag, fmask);

    // in-proj: M=32768, N=1536, K=512; epilogue -> qphi/kpb/vmb (bf16)
    hipLaunchKernelGGL(gemm_mfma256, dim3(1536 / 256, NROW / 256), dim3(512), 0, stream,
                       qb, D_, wib, D_, b_in, D_, 0, fmask,
                       qphi, kpb, vmb, (float*)nullptr);

    hipLaunchKernelGGL(kv_reduce, dim3(32, 16), dim3(256), 0, stream, kpb, vmb, part_kv, part_ks);
    hipLaunchKernelGGL(kv_reduce2, dim3(512), dim3(256), 0, stream,
                       part_kv, part_ks, kvTb, ksumb);

    // attn: MFMA, writes into qb (dead after in-proj)
    hipLaunchKernelGGL(apply_attn_mfma, dim3(32, S_ / 128), dim3(256), 0, stream,
                       qphi, kvTb, ksumb, qb);

    // out-proj: M=32768, N=512, K=512 -> fp32 d_out
    hipLaunchKernelGGL(gemm_mfma256, dim3(512 / 256, NROW / 256), dim3(512), 0, stream,
                       qb, D_, wob, D_, b_out, D_, 1, (const float*)nullptr,
                       (unsigned short*)nullptr, (unsigned short*)nullptr,
                       (unsigned short*)nullptr, out);
}

// Round 9
// 386.517 us; speedup vs baseline: 1.0508x; 1.0508x over previous
//
#include <hip/hip_runtime.h>
#include <cstddef>

#define B_   4
#define S_   8192
#define D_   512
#define H_   8
#define HD_  64
#define NROW (B_ * S_)              // 32768
#define NQ   ((size_t)NROW * D_)    // 16777216 elements per q/k/v buffer

typedef __attribute__((ext_vector_type(4))) float  f32x4;
typedef __attribute__((ext_vector_type(8))) short  s16x8;
typedef __attribute__((ext_vector_type(4))) unsigned short u16x4;
typedef __attribute__((ext_vector_type(8))) unsigned short u16x8;

__device__ __forceinline__ float phi_f(float x) {
    return x > 0.0f ? x + 1.0f : expf(x);   // elu(x)+1
}
__device__ __forceinline__ float bf2f(unsigned short u) {
    return __uint_as_float(((unsigned int)u) << 16);
}
__device__ __forceinline__ unsigned short f2bf(float f) {
    unsigned int u = __float_as_uint(f);
    u += 0x7fffu + ((u >> 16) & 1u);        // round-to-nearest-even
    return (unsigned short)(u >> 16);
}

#define GLOBAL_AS(p) ((const __attribute__((address_space(1))) void*)(p))
#define LDS_AS(p)    ((__attribute__((address_space(3))) void*)(p))

// ---------------------------------------------------------------------------
// Mask layout detector: 1 = byte-per-element (bool), 0 = 4-byte layout.
// R11: vectorized — uint4 x8 per thread (was serial strided byte walk on one
// wave, ~8 µs latency-bound).  Rule: byte layout iff any byte at position
// 1..3 within a 4B word is nonzero ((w & 0xFFFFFF00) != 0); int layout words
// are 0/1 so the mask is always 0.  At 10% density over 3*8192 candidate
// bytes this fires with certainty for byte layout (same as original rule).
// ---------------------------------------------------------------------------
__global__ void detect_mask(const unsigned char* __restrict__ m, int* __restrict__ flag) {
    __shared__ int sany;
    if (threadIdx.x == 0) sany = 0;
    __syncthreads();
    const uint4* mw = (const uint4*)m;      // 32768 B = 2048 uint4
    unsigned int any = 0;
    #pragma unroll
    for (int r = 0; r < 8; ++r) {
        const uint4 w = mw[r * 256 + threadIdx.x];
        any |= (w.x | w.y | w.z | w.w) & 0xFFFFFF00u;
    }
    if (any) atomicOr(&sany, 1);
    __syncthreads();
    if (threadIdx.x == 0) *flag = sany ? 1 : 0;
}

// ---------------------------------------------------------------------------
// Convert query/w_in/w_out -> bf16; mask -> float (1.0 keep / 0.0 ignore).
// ---------------------------------------------------------------------------
__global__ __launch_bounds__(256) void convert_all(
    const float* __restrict__ q,  unsigned short* __restrict__ qb,
    const float* __restrict__ wi, unsigned short* __restrict__ wib,
    const float* __restrict__ wo, unsigned short* __restrict__ wob,
    const unsigned char* __restrict__ kpm, const int* __restrict__ flag,
    float* __restrict__ fmask)
{
    const size_t i = (size_t)blockIdx.x * 256 + threadIdx.x;
    {   // query: 16777216 / 4 = 4194304 threads exactly
        const float4 v = *(const float4*)&q[i * 4];
        u16x4 o; o.x = f2bf(v.x); o.y = f2bf(v.y); o.z = f2bf(v.z); o.w = f2bf(v.w);
        *(u16x4*)&qb[i * 4] = o;
    }
    if (i < 786432 / 4) {
        const float4 v = *(const float4*)&wi[i * 4];
        u16x4 o; o.x = f2bf(v.x); o.y = f2bf(v.y); o.z = f2bf(v.z); o.w = f2bf(v.w);
        *(u16x4*)&wib[i * 4] = o;
    }
    if (i < 262144 / 4) {
        const float4 v = *(const float4*)&wo[i * 4];
        u16x4 o; o.x = f2bf(v.x); o.y = f2bf(v.y); o.z = f2bf(v.z); o.w = f2bf(v.w);
        *(u16x4*)&wob[i * 4] = o;
    }
    if (i < NROW) {
        const bool ignore = (*flag) ? (kpm[i] != 0) : (((const int*)kpm)[i] != 0);
        fmask[i] = ignore ? 0.0f : 1.0f;
    }
}

// ---------------------------------------------------------------------------
// bf16 MFMA GEMM (R8, verified): C[m][n] = sum_k A[m][k]*B[n][k] + bias[n].
// 128x128 tile, BK=32, 256 thr = 2x2 waves, 4x4 frags of 16x16x32_bf16.
// T1 XCD swizzle; T2 swizzle via pre-swizzled global source (conflicts = 0,
// verified R3); depth-2 pipeline, 3 LDS buffers, counted vmcnt(4) + raw
// s_barrier (verified R4: passed, stable; ~98 µs in-proj).
// R9/R10 lesson: the 256² 8-phase schedule LOSES at this shape (K=512 ->
// niter=4; prologue never amortizes; sched_barrier pinning kills overlap).
// mode 0: in-proj epilogue -> phi / phi*mask / *mask into q/k/v bf16 buffers.
// mode 1: out-proj epilogue -> fp32 to Cout.
// ---------------------------------------------------------------------------
__global__ __launch_bounds__(256) void gemm_mfma(
    const unsigned short* __restrict__ A,  int lda,
    const unsigned short* __restrict__ Bw, int ldb,
    const float* __restrict__ bias, int K, int mode,
    const float* __restrict__ fmask,
    unsigned short* __restrict__ Cq,
    unsigned short* __restrict__ Ck,
    unsigned short* __restrict__ Cv,
    float* __restrict__ Cout)
{
    __shared__ __align__(16) unsigned short As[3][128 * 32];  // [buf][m][k], 64B rows
    __shared__ __align__(16) unsigned short Bs[3][128 * 32];  // [buf][n][k]
    __shared__ float fm[128];

    const int t    = threadIdx.x;
    const int lane = t & 63;
    const int wave = t >> 6;            // 0..3
    const int wm   = wave & 1;          // wave m-offset (x64)
    const int wn   = wave >> 1;         // wave n-offset (x64)

    // T1 XCD swizzle (bijective: nwg % 8 == 0 for both launches)
    const int nbx = gridDim.x;
    const int nwg = nbx * gridDim.y;
    int id = blockIdx.y * nbx + blockIdx.x;
    id = (id & 7) * (nwg >> 3) + (id >> 3);
    const int m0 = (id / nbx) * 128;
    const int n0 = (id % nbx) * 128;

    if (mode == 0 && t < 128) fm[t] = fmask[m0 + t];

    f32x4 acc[4][4] = {};

    // staging: lane l -> LDS row l>>2, physical chunk l&3 (linear dest);
    // source chunk pre-swizzled so LDS(r,c') = global(r, c' ^ ((r>>1)&3))
    const int sr  = lane >> 2;                              // row-in-16
    const int skc = (((lane & 3) ^ ((lane >> 3) & 3))) * 8; // swizzled src chunk (elems)

    const int nt = K >> 5;              // K-steps of 32 (16 here)

    #define STAGE(kt_, buf_)                                                            \
        do {                                                                            \
            const int k0_ = (kt_) << 5;                                                 \
            _Pragma("unroll")                                                           \
            for (int j = 0; j < 2; ++j) {                                               \
                const int row = wave * 32 + j * 16;                                     \
                const unsigned short* g = A + (size_t)(m0 + row + sr) * lda + k0_ + skc;\
                __builtin_amdgcn_global_load_lds(GLOBAL_AS(g),                          \
                    LDS_AS(&As[(buf_)][row * 32]), 16, 0, 0);                           \
            }                                                                           \
            _Pragma("unroll")                                                           \
            for (int j = 0; j < 2; ++j) {                                               \
                const int row = wave * 32 + j * 16;                                     \
                const unsigned short* g = Bw + (size_t)(n0 + row + sr) * ldb + k0_ + skc;\
                __builtin_amdgcn_global_load_lds(GLOBAL_AS(g),                          \
                    LDS_AS(&Bs[(buf_)][row * 32]), 16, 0, 0);                           \
            }                                                                           \
        } while (0)

    // prologue: stage tiles 0 and 1 (no drain, no barrier yet)
    STAGE(0, 0);
    STAGE(1, 1);

    // frag read addressing (swizzle-aware)
    const int fr = lane & 15;           // m (or n) within 16
    const int cn = lane >> 4;           // logical 16B chunk 0..3
    const int fo = (cn ^ ((fr >> 1) & 3)) * 8;  // physical chunk -> element offset

    int cur = 0;                        // kt % 3
    for (int kt = 0; kt < nt; ++kt) {
        if (kt + 1 < nt) asm volatile("s_waitcnt vmcnt(4)" ::: "memory");
        else             asm volatile("s_waitcnt vmcnt(0)" ::: "memory");
        __builtin_amdgcn_s_barrier();   // raw barrier: no compiler vmcnt(0) drain

        if (kt + 2 < nt) {
            int nb = cur + 2; if (nb >= 3) nb -= 3;
            STAGE(kt + 2, nb);
        }

        s16x8 af[4], bf[4];
        #pragma unroll
        for (int i = 0; i < 4; ++i)
            af[i] = *(const s16x8*)&As[cur][(wm * 64 + i * 16 + fr) * 32 + fo];
        #pragma unroll
        for (int j = 0; j < 4; ++j)
            bf[j] = *(const s16x8*)&Bs[cur][(wn * 64 + j * 16 + fr) * 32 + fo];
        #pragma unroll
        for (int i = 0; i < 4; ++i)
            #pragma unroll
            for (int j = 0; j < 4; ++j)
                acc[i][j] = __builtin_amdgcn_mfma_f32_16x16x32_bf16(af[i], bf[j], acc[i][j], 0, 0, 0);

        if (++cur == 3) cur = 0;
    }
    #undef STAGE

    // Epilogue. C/D layout: n = lane&15, m = (lane>>4)*4 + reg.
    const int col  = lane & 15;
    const int rowq = (lane >> 4) * 4;
    float bj[4];
    #pragma unroll
    for (int j = 0; j < 4; ++j) bj[j] = bias[n0 + wn * 64 + j * 16 + col];

    if (mode == 1) {
        #pragma unroll
        for (int i = 0; i < 4; ++i)
            #pragma unroll
            for (int r = 0; r < 4; ++r) {
                const int m = m0 + wm * 64 + i * 16 + rowq + r;
                #pragma unroll
                for (int j = 0; j < 4; ++j) {
                    const int n = n0 + wn * 64 + j * 16 + col;
                    Cout[(size_t)m * D_ + n] = acc[i][j][r] + bj[j];
                }
            }
    } else {
        const int region = n0 >> 9;     // 0:q 1:k 2:v (BN=128 divides 512)
        unsigned short* Cb = region == 0 ? Cq : (region == 1 ? Ck : Cv);
        #pragma unroll
        for (int i = 0; i < 4; ++i)
            #pragma unroll
            for (int r = 0; r < 4; ++r) {
                const int ml = wm * 64 + i * 16 + rowq + r;
                const int m  = m0 + ml;
                const float mk = fm[ml];
                #pragma unroll
                for (int j = 0; j < 4; ++j) {
                    const int n  = (n0 & 511) + wn * 64 + j * 16 + col;
                    float v = acc[i][j][r] + bj[j];
                    if (region == 0)      v = phi_f(v);
                    else if (region == 1) v = phi_f(v) * mk;
                    else                  v = v * mk;
                    Cb[(size_t)m * D_ + n] = f2bf(v);
                }
            }
    }
}

// ---------------------------------------------------------------------------
// Partial kv = k^T v (64x64) and k_sum per (head, S-chunk, wave-group).
// 8x8 per-thread tile; 4-wave s-split; padded LDS rows; u16x8 staging.
// R11 (T14 async-stage): the next-iteration global load is issued AFTER the
// second barrier, so it sits in flight under the ~1500-cy compute phase.
// Previously it was issued right before the first __syncthreads(), whose
// conservative vmcnt(0) drain exposed the full load latency every iteration
// (32x per block at only 2 blocks/CU of TLP).
// ---------------------------------------------------------------------------
__global__ __launch_bounds__(256) void kv_reduce(
    const unsigned short* __restrict__ kbuf,   // [NROW][512] bf16
    const unsigned short* __restrict__ vbuf,
    float* __restrict__ part_kv,               // [32*64][4096]
    float* __restrict__ part_ks)               // [32*64][64]
{
    const int bh = blockIdx.x, chunk = blockIdx.y;   // chunk 0..15
    const int b = bh >> 3, h = bh & 7;

    __shared__ __align__(16) float Ks[16][68];   // pad 64->68: staging writes conflict-free
    __shared__ __align__(16) float Vs[16][68];

    const int t    = threadIdx.x;
    const int wave = t >> 6;            // ss-group 0..3
    const int lane = t & 63;
    const int tx   = lane & 7;          // e-octet
    const int ty   = lane >> 3;         // d-octet

    // staging: threads 0..127 load K, 128..255 load V; 8 bf16 (16B) each
    const int sr = (t & 127) >> 3;      // row 0..15
    const int sc = (t & 7) * 8;         // col 0,8,..,56
    const unsigned short* src = (t < 128 ? kbuf : vbuf) + (size_t)b * S_ * D_ + h * HD_;
    float (*dst)[68] = (t < 128) ? Ks : Vs;

    float acc[8][8] = {};
    float ks[8] = {};
    const int s0 = chunk * (S_ / 16);   // 512 rows per chunk
    const int NIT = 32;                 // 32 iterations of 16 rows

    u16x8 x = *(const u16x8*)&src[(size_t)(s0 + sr) * D_ + sc];

    for (int it = 0; it < NIT; ++it) {
        __syncthreads();                // previous compute done, LDS free
        float4 f0, f1;
        f0.x = bf2f(x[0]); f0.y = bf2f(x[1]); f0.z = bf2f(x[2]); f0.w = bf2f(x[3]);
        f1.x = bf2f(x[4]); f1.y = bf2f(x[5]); f1.z = bf2f(x[6]); f1.w = bf2f(x[7]);
        *(float4*)&dst[sr][sc]     = f0;
        *(float4*)&dst[sr][sc + 4] = f1;
        __syncthreads();                // staging complete
        u16x8 xn = {};
        if (it + 1 < NIT)               // prefetch issued BEFORE compute; its
            xn = *(const u16x8*)&src[(size_t)(s0 + (it + 1) * 16 + sr) * D_ + sc];
        #pragma unroll
        for (int ss0 = 0; ss0 < 4; ++ss0) {
            const int ss = wave + ss0 * 4;
            const float4 a0 = *(const float4*)&Ks[ss][ty * 8];
            const float4 a1 = *(const float4*)&Ks[ss][ty * 8 + 4];
            const float4 v0 = *(const float4*)&Vs[ss][tx * 8];
            const float4 v1 = *(const float4*)&Vs[ss][tx * 8 + 4];
            const float av[8] = {a0.x, a0.y, a0.z, a0.w, a1.x, a1.y, a1.z, a1.w};
            const float vv[8] = {v0.x, v0.y, v0.z, v0.w, v1.x, v1.y, v1.z, v1.w};
            #pragma unroll
            for (int i2 = 0; i2 < 8; ++i2)
                #pragma unroll
                for (int j2 = 0; j2 < 8; ++j2)
                    acc[i2][j2] += av[i2] * vv[j2];
            if (tx == 0) {
                #pragma unroll
                for (int i2 = 0; i2 < 8; ++i2) ks[i2] += av[i2];
            }
        }
        x = xn;                         // consumed next iter (after this compute)
    }

    const int p = bh * 64 + chunk * 4 + wave;    // partial index
    float* pk = part_kv + (size_t)p * 4096;
    #pragma unroll
    for (int i2 = 0; i2 < 8; ++i2) {
        #pragma unroll
        for (int j4 = 0; j4 < 2; ++j4) {
            float4 o;
            o.x = acc[i2][j4 * 4 + 0]; o.y = acc[i2][j4 * 4 + 1];
            o.z = acc[i2][j4 * 4 + 2]; o.w = acc[i2][j4 * 4 + 3];
            *(float4*)&pk[(ty * 8 + i2) * 64 + tx * 8 + j4 * 4] = o;
        }
    }
    if (tx == 0) {
        float* ps = part_ks + (size_t)p * 64;
        #pragma unroll
        for (int i2 = 0; i2 < 8; ++i2) ps[ty * 8 + i2] = ks[i2];
    }
}

// ---------------------------------------------------------------------------
// Sum 64 partials; emit kv TRANSPOSED in bf16 ([e][d] = MFMA B[n][k] layout)
// and ksum in bf16.
// ---------------------------------------------------------------------------
__global__ void kv_reduce2(const float* __restrict__ part_kv,
                           const float* __restrict__ part_ks,
                           unsigned short* __restrict__ kvT,    // [32][64][64]
                           unsigned short* __restrict__ ksumb)  // [32][64]
{
    const int i = blockIdx.x * 256 + threadIdx.x;   // 512 blocks -> 131072 exact
    if (i < 32 * 4096) {
        const int bh = i >> 12, de = i & 4095;
        const int d = de >> 6, e = de & 63;
        float s = 0.0f;
        #pragma unroll
        for (int c = 0; c < 64; ++c) s += part_kv[(size_t)(bh * 64 + c) * 4096 + de];
        kvT[bh * 4096 + e * 64 + d] = f2bf(s);
    }
    if (i < 32 * 64) {
        const int bh = i >> 6, e = i & 63;
        float s = 0.0f;
        #pragma unroll
        for (int c = 0; c < 64; ++c) s += part_ks[(size_t)(bh * 64 + c) * 64 + e];
        ksumb[i] = f2bf(s);
    }
}

// ---------------------------------------------------------------------------
// attn via MFMA, no LDS, no barriers.
// Per block: 128 rows x one head.  numerator: A=qphi[m][k=d] (bf16, contig),
// B=kvT[n=e][k=d].  Denominator: one extra MFMA per m-frag with a B-frag that
// broadcasts ksum across all 16 n-cols -> every lane holds its rows' own
// denominator in the accumulator (division is lane-local).
// ---------------------------------------------------------------------------
__global__ __launch_bounds__(256) void apply_attn_mfma(
    const unsigned short* __restrict__ qphi,   // [NROW][512] bf16 (phi'd)
    const unsigned short* __restrict__ kvT,    // [32][64][64] bf16
    const unsigned short* __restrict__ ksumb,  // [32][64] bf16
    unsigned short* __restrict__ attnb)        // [NROW][512] bf16
{
    const int bh = blockIdx.x;
    const int b  = bh >> 3, h = bh & 7;
    const int m0 = blockIdx.y * 128;

    const int t    = threadIdx.x;
    const int lane = t & 63;
    const int wave = t >> 6;            // rows m0 + wave*32 .. +32
    const int fr   = lane & 15;
    const int fk   = (lane >> 4) * 8;
    const int row0 = m0 + wave * 32;

    const unsigned short* Ah = qphi + (size_t)(b * S_ + row0) * D_ + h * HD_;
    const unsigned short* Bh = kvT + bh * 4096;
    const unsigned short* Kh = ksumb + bh * 64;

    s16x8 af[2][2], bfr[2][4], bd[2];
    #pragma unroll
    for (int kc = 0; kc < 2; ++kc) {
        #pragma unroll
        for (int i = 0; i < 2; ++i)
            af[kc][i] = *(const s16x8*)&Ah[(size_t)(i * 16 + fr) * D_ + kc * 32 + fk];
        #pragma unroll
        for (int j = 0; j < 4; ++j)
            bfr[kc][j] = *(const s16x8*)&Bh[(j * 16 + fr) * 64 + kc * 32 + fk];
        bd[kc] = *(const s16x8*)&Kh[kc * 32 + fk];   // broadcast over fr
    }

    f32x4 acc[2][4] = {};
    f32x4 accd[2] = {};
    #pragma unroll
    for (int kc = 0; kc < 2; ++kc)
        #pragma unroll
        for (int i = 0; i < 2; ++i) {
            #pragma unroll
            for (int j = 0; j < 4; ++j)
                acc[i][j] = __builtin_amdgcn_mfma_f32_16x16x32_bf16(af[kc][i], bfr[kc][j], acc[i][j], 0, 0, 0);
            accd[i] = __builtin_amdgcn_mfma_f32_16x16x32_bf16(af[kc][i], bd[kc], accd[i], 0, 0, 0);
        }

    // C/D layout: col = lane&15 (=fr), row = (lane>>4)*4 + reg
    const int rq = (lane >> 4) * 4;
    #pragma unroll
    for (int i = 0; i < 2; ++i)
        #pragma unroll
        for (int r = 0; r < 4; ++r) {
            const float inv = 1.0f / fmaxf(accd[i][r], 1e-6f);
            const size_t row = (size_t)(b * S_ + row0 + i * 16 + rq + r);
            #pragma unroll
            for (int j = 0; j < 4; ++j)
                attnb[row * D_ + h * HD_ + j * 16 + fr] = f2bf(acc[i][j][r] * inv);
        }
}

// ---------------------------------------------------------------------------
extern "C" void kernel_launch(void* const* d_in, const int* in_sizes, int n_in,
                              void* d_out, int out_size, void* d_ws, size_t ws_size,
                              hipStream_t stream)
{
    const float* query       = (const float*)d_in[0];
    const unsigned char* kpm = (const unsigned char*)d_in[3];
    const float* w_in        = (const float*)d_in[4];
    const float* b_in        = (const float*)d_in[5];
    const float* w_out       = (const float*)d_in[6];
    const float* b_out       = (const float*)d_in[7];
    float* out = (float*)d_out;

    // workspace layout (attn aliases qb, which is dead after in-proj)
    unsigned short* qb    = (unsigned short*)d_ws;          // query bf16 / attn bf16  33.5 MB
    unsigned short* qphi  = qb    + NQ;                     // phi(q)         33.5 MB
    unsigned short* kpb   = qphi  + NQ;                     // phi(k)*mask    33.5 MB
    unsigned short* vmb   = kpb   + NQ;                     // v*mask         33.5 MB
    unsigned short* wib   = vmb   + NQ;                     // w_in bf16       1.6 MB
    unsigned short* wob   = wib   + 1536 * 512;             // w_out bf16      0.5 MB
    float* fmask   = (float*)(wob + 512 * 512);             // 128 KB
    float* part_kv = fmask + NROW;                          // 32*64 partials: 32 MB
    float* part_ks = part_kv + (size_t)2048 * 4096;         // 512 KB
    unsigned short* kvTb  = (unsigned short*)(part_ks + 2048 * 64);  // 256 KB
    unsigned short* ksumb = kvTb + 32 * 4096;               // 4 KB
    int*   flag    = (int*)(ksumb + 32 * 64);

    hipLaunchKernelGGL(detect_mask, dim3(1), dim3(256), 0, stream, kpm, flag);
    hipLaunchKernelGGL(convert_all, dim3(16384), dim3(256), 0, stream,
                       query, qb, w_in, wib, w_out, wob, kpm, flag, fmask);

    // in-proj: M=32768, N=1536, K=512; epilogue -> qphi/kpb/vmb (bf16)
    hipLaunchKernelGGL(gemm_mfma, dim3(1536 / 128, NROW / 128), dim3(256), 0, stream,
                       qb, D_, wib, D_, b_in, D_, 0, fmask,
                       qphi, kpb, vmb, (float*)nullptr);

    hipLaunchKernelGGL(kv_reduce, dim3(32, 16), dim3(256), 0, stream, kpb, vmb, part_kv, part_ks);
    hipLaunchKernelGGL(kv_reduce2, dim3(512), dim3(256), 0, stream,
                       part_kv, part_ks, kvTb, ksumb);

    // attn: MFMA, writes into qb (dead after in-proj)
    hipLaunchKernelGGL(apply_attn_mfma, dim3(32, S_ / 128), dim3(256), 0, stream,
                       qphi, kvTb, ksumb, qb);

    // out-proj: M=32768, N=512, K=512 -> fp32 d_out
    hipLaunchKernelGGL(gemm_mfma, dim3(512 / 128, NROW / 128), dim3(256), 0, stream,
                       qb, D_, wob, D_, b_out, D_, 1, (const float*)nullptr,
                       (unsigned short*)nullptr, (unsigned short*)nullptr,
                       (unsigned short*)nullptr, out);
}